// Round 3
// baseline (444.990 us; speedup 1.0000x reference)
//
#include <hip/hip_runtime.h>
#include <math.h>

#define K_DIM 8192
#define M_DIM 8192
#define N_DIM 8
#define RED_BLOCKS 2048      // pass-1 blocks; each owns 4 W rows (128 KiB)
#define KC 2048              // pass-2 K chunk staged in LDS (8 x 2048 floats = 64 KiB)

// Prior on s_w = 1/mean|W|: statistically 62.666 +- ~0.01% for this input.
// Codes are only trusted if the true s_w is within +-0.25% of the prior;
// otherwise pass 2 falls back to exact recompute of EVERY weight (correct,
// slower, never triggered in practice). Weights with |w*S_PRIOR| in
// [AMB_LO, AMB_HI] are always recomputed exactly (~0.2% of weights).
#define S_PRIOR 62.666f
#define AMB_LO  0.4985f
#define AMB_HI  0.5015f

// ---------------------------------------------------------------------------
// Pass 1: stream W once. Per block: (a) |W| partial sum (double), (b) 2-bit
// ternary codes vs prior band, (c) blocks 0..255 also quantize activations.
// code fields per weight (2 bits): 0 -> 0, 1 -> +1, 2 -> -1, 3 -> ambiguous.
// ---------------------------------------------------------------------------
__device__ __forceinline__ unsigned int enc1(float w) {
    float p = w * S_PRIOR;
    float ap = fabsf(p);
    if (ap < AMB_LO) return 0u;
    if (ap > AMB_HI) return (p > 0.0f) ? 1u : 2u;
    return 3u;
}

__global__ __launch_bounds__(256) void k_pass1(const float4* __restrict__ W4,
                                               const float* __restrict__ x,
                                               double* __restrict__ partials,
                                               float* __restrict__ xh,
                                               unsigned char* __restrict__ codes) {
    const size_t base = (size_t)blockIdx.x * 8192 + threadIdx.x;
    float s0 = 0.f, s1 = 0.f, s2 = 0.f, s3 = 0.f;
    #pragma unroll 8
    for (int j = 0; j < 32; ++j) {
        float4 v = W4[base + 256 * j];
        s0 += fabsf(v.x); s1 += fabsf(v.y);
        s2 += fabsf(v.z); s3 += fabsf(v.w);
        unsigned int c = enc1(v.x) | (enc1(v.y) << 2) |
                         (enc1(v.z) << 4) | (enc1(v.w) << 6);
        codes[base + 256 * j] = (unsigned char)c;
    }
    float s = (s0 + s1) + (s2 + s3);
    #pragma unroll
    for (int off = 32; off > 0; off >>= 1) s += __shfl_xor(s, off, 64);
    __shared__ float sm[4];
    if ((threadIdx.x & 63) == 0) sm[threadIdx.x >> 6] = s;
    __syncthreads();
    if (threadIdx.x == 0) {
        double t = ((double)sm[0] + (double)sm[1]) +
                   ((double)sm[2] + (double)sm[3]);
        partials[blockIdx.x] = t;
    }

    // fused activation quantization: one wave == one 64-group
    if (blockIdx.x < (N_DIM * K_DIM) / 256) {
        int idx = blockIdx.x * 256 + threadIdx.x;
        float v = x[idx];
        float a = fabsf(v);
        #pragma unroll
        for (int off = 32; off > 0; off >>= 1)
            a = fmaxf(a, __shfl_xor(a, off, 64));
        float scale = fmaxf(a / 127.0f, 1e-8f);
        xh[idx] = rintf(v / scale) * scale;
    }
}

// ---------------------------------------------------------------------------
// Pass 2: replicated deterministic scalar reduce -> exact s_w / w_deq, then
// decode-accumulate GEMV from 2-bit codes. x_hat chunk staged in LDS.
// Ambiguous (or prior-violating) weights recomputed exactly from pristine W.
// ---------------------------------------------------------------------------
__device__ __forceinline__ float quant1(float w, float s_w) {
    return fminf(1.0f, fmaxf(-1.0f, rintf(w * s_w)));
}

__global__ __launch_bounds__(256) void k_pass2(const float* __restrict__ W,
                                               const float* __restrict__ xh,
                                               const unsigned char* __restrict__ codes,
                                               const double* __restrict__ partials,
                                               float* __restrict__ out) {
    __shared__ float lds[N_DIM * KC];   // 64 KiB
    // --- replicated reduce (identical order in every block -> bit-identical s_w)
    double s = 0.0;
    #pragma unroll
    for (int j = 0; j < RED_BLOCKS / 256; ++j)
        s += partials[threadIdx.x + j * 256];
    #pragma unroll
    for (int off = 32; off > 0; off >>= 1) s += __shfl_xor(s, off, 64);
    __shared__ double smd[4];
    if ((threadIdx.x & 63) == 0) smd[threadIdx.x >> 6] = s;
    __syncthreads();
    const double tot = (smd[0] + smd[1]) + (smd[2] + smd[3]);
    const float meanf = (float)(tot / (double)((long long)M_DIM * K_DIM));
    const float s_w = 1.0f / fmaxf(meanf, 1e-5f);   // reference fp32 chain
    const float w_deq = 1.0f / s_w;
    const bool prior_bad = !(s_w >= 0.9975f * S_PRIOR && s_w <= 1.0025f * S_PRIOR);

    const int wave = threadIdx.x >> 6;
    const int lane = threadIdx.x & 63;
    const int m0 = blockIdx.x * 16 + wave * 4;   // 4 rows per wave

    float acc[4][8];
    #pragma unroll
    for (int r = 0; r < 4; ++r)
        #pragma unroll
        for (int n = 0; n < 8; ++n) acc[r][n] = 0.0f;

    const float4* xh4 = (const float4*)xh;

    for (int c = 0; c < K_DIM / KC; ++c) {   // 4 chunks
        __syncthreads();   // protect LDS against previous chunk's readers
        // stage x_hat[0:8, c*KC : (c+1)*KC] into LDS (4096 float4)
        #pragma unroll
        for (int i = 0; i < 16; ++i) {
            int sIdx = threadIdx.x + 256 * i;       // 0..4095
            int n = sIdx >> 9;                      // / 512
            int q4 = sIdx & 511;
            ((float4*)lds)[sIdx] = xh4[n * (K_DIM / 4) + c * (KC / 4) + q4];
        }
        __syncthreads();

        #pragma unroll 2
        for (int j = 0; j < KC / 256; ++j) {        // 8 iterations
            const int kk = 4 * lane + 256 * j;      // k within chunk
            const int kglob = c * KC + kk;
            const int cb = c * (KC / 4) + lane + 64 * j;   // code byte in row

            float q[4][4];
            #pragma unroll
            for (int r = 0; r < 4; ++r) {
                unsigned int cc = codes[(size_t)(m0 + r) * (K_DIM / 4) + cb];
                unsigned int b0 = cc & 0x55u;
                unsigned int b1 = (cc >> 1) & 0x55u;
                #pragma unroll
                for (int i = 0; i < 4; ++i)
                    q[r][i] = (float)((int)((b0 >> (2 * i)) & 1u) -
                                      (int)((b1 >> (2 * i)) & 1u));
                unsigned int amb = b0 & b1;          // fields == 3
                if (amb != 0u || prior_bad) {
                    const float* wr = W + (size_t)(m0 + r) * K_DIM + kglob;
                    #pragma unroll
                    for (int i = 0; i < 4; ++i)
                        if ((amb & (1u << (2 * i))) != 0u || prior_bad)
                            q[r][i] = quant1(wr[i], s_w);
                }
            }

            #pragma unroll
            for (int n = 0; n < 8; ++n) {
                float4 xv = *(const float4*)(lds + n * KC + kk);
                #pragma unroll
                for (int r = 0; r < 4; ++r) {
                    acc[r][n] = fmaf(q[r][0], xv.x, acc[r][n]);
                    acc[r][n] = fmaf(q[r][1], xv.y, acc[r][n]);
                    acc[r][n] = fmaf(q[r][2], xv.z, acc[r][n]);
                    acc[r][n] = fmaf(q[r][3], xv.w, acc[r][n]);
                }
            }
        }
    }

    // cross-lane reduction + store
    #pragma unroll
    for (int r = 0; r < 4; ++r) {
        #pragma unroll
        for (int n = 0; n < 8; ++n) {
            float v = acc[r][n];
            #pragma unroll
            for (int off = 32; off > 0; off >>= 1) v += __shfl_xor(v, off, 64);
            acc[r][n] = v;
        }
    }
    if (lane == 0) {
        #pragma unroll
        for (int r = 0; r < 4; ++r)
            #pragma unroll
            for (int n = 0; n < 8; ++n)
                out[n * M_DIM + (m0 + r)] = w_deq * acc[r][n];
    }
}

// ---------------------------------------------------------------------------
extern "C" void kernel_launch(void* const* d_in, const int* in_sizes, int n_in,
                              void* d_out, int out_size, void* d_ws, size_t ws_size,
                              hipStream_t stream) {
    const float* x = (const float*)d_in[0];   // [8, 8192] fp32
    const float* W = (const float*)d_in[1];   // [8192, 8192] fp32
    float* out = (float*)d_out;               // [8, 8192] fp32

    // ws layout: [0,16K) partials; [32K, 32K+256K) x_hat; [1M, 1M+16M) codes
    double* partials = (double*)d_ws;
    float* xh = (float*)((char*)d_ws + (32 << 10));
    unsigned char* codes = (unsigned char*)d_ws + (1 << 20);

    k_pass1<<<RED_BLOCKS, 256, 0, stream>>>((const float4*)W, x, partials, xh, codes);
    k_pass2<<<M_DIM / 16, 256, 0, stream>>>(W, xh, codes, partials, out);
}